// Round 14
// baseline (4275.334 us; speedup 1.0000x reference)
//
#include <hip/hip_runtime.h>
#include <math.h>

// Sizes fixed by the problem.
#define B_TOT 131072
#define M_N   1024
#define BS    128      // Cholesky block size
#define NBK   8        // M_N / BS

typedef float    f32x4 __attribute__((ext_vector_type(4)));
typedef _Float16 f16x8 __attribute__((ext_vector_type(8)));

// Workspace layout (bytes). Total ~17 MB.
enum : size_t {
    OFF_KF  = 0,                          // fp32 K (Schur-updated)  4 MB
    OFF_LF  = (size_t)4 << 20,            // fp32 L off-diag strips  4 MB
    OFF_WF  = (size_t)8 << 20,            // fp32 W = L^-1 (lower)   4 MB
    OFF_WPH = (size_t)12 << 20,           // fp16 W packed hi        2 MB
    OFF_WPL = (size_t)14 << 20,           // fp16 W packed lo        2 MB
    OFF_PF  = (size_t)16 << 20,           // fp32 params (6)
    OFF_ZT  = ((size_t)16 << 20) + 256,   // fp32 Zs_t [5][1024]     20 KB
};

__device__ __constant__ float c_zscale[5] = {0.15f, 0.1f, 0.05f, 800.0f, 20.0f};
__device__ __constant__ float c_zshift[5] = {0.0f, 0.0f, 0.0f, 600.0f, 5.0f};

// ---------------- fused: params + Zst + K = matern52 + jitter (fp32) ----------------
__global__ __launch_bounds__(256) void k_build(const float* __restrict__ log_ls,
                                               const float* __restrict__ log_var,
                                               const float* __restrict__ Zraw,
                                               float* __restrict__ Kf,
                                               float* __restrict__ pf,
                                               float* __restrict__ Zst) {
    __shared__ float ps[6];
    __shared__ float zsi[5];
    int tid = threadIdx.x;
    if (tid < 5) ps[tid] = 1.0f / (__expf(log_ls[tid]) + 1e-8f);
    if (tid == 5) ps[5] = __expf(log_var[0]);
    __syncthreads();
    int i = blockIdx.x >> 2;
    int j = (blockIdx.x & 3) * 256 + tid;
    if (tid < 5) zsi[tid] = (Zraw[i * 5 + tid] * c_zscale[tid] + c_zshift[tid]) * ps[tid];
    __syncthreads();
    float d2 = 0.0f;
#pragma unroll
    for (int d = 0; d < 5; ++d) {
        float zj = (Zraw[j * 5 + d] * c_zscale[d] + c_zshift[d]) * ps[d];
        float df = zsi[d] - zj;
        d2 += df * df;
    }
    float dd = d2 + 1e-8f;
    float dist = sqrtf(dd);
    float s = 2.23606798f * dist;
    float v = ps[5] * (1.0f + s + 1.66666667f * dd) * __expf(-s);
    if (i == j) v += 1e-4f;
    Kf[(size_t)i * M_N + j] = v;
    if (blockIdx.x < 4) {
        int m = blockIdx.x * 256 + tid;
#pragma unroll
        for (int d = 0; d < 5; ++d)
            Zst[d * M_N + m] = (Zraw[m * 5 + d] * c_zscale[d] + c_zshift[d]) * ps[d];
    }
    if (blockIdx.x == 4 && tid < 6) pf[tid] = ps[tid];
}

// ---------------- diag factor + inverse: wave-lockstep register panels ----------------
// Panel factor runs entirely on wave 0 in registers (2 rows/lane, shfl broadcasts,
// ALL register indices compile-time); trailing rank-8 update by all nthr threads.
static __device__ void d_diag_fast(float (*As)[129], float* sinv,
                                   float* __restrict__ Wf, int r0, int tid, int nthr) {
    int lane = tid & 63;
    int wav  = tid >> 6;
    for (int p = 0; p < 16; ++p) {
        int j0 = p * 8;
        if (wav == 0) {
            int sc = j0 >> 6;               // which register slot holds the diag rows
            float a0[8], a1[8];
#pragma unroll
            for (int c = 0; c < 8; ++c) {
                a0[c] = As[lane][j0 + c];
                a1[c] = As[lane + 64][j0 + c];
            }
#pragma unroll
            for (int j = 0; j < 8; ++j) {
                int jrow = j0 + j;
                int ol = jrow & 63;
                float vd  = sc ? a1[j] : a0[j];
                float ajj = __shfl(vd, ol);
                float dg  = sqrtf(ajj);
                float si  = 1.0f / dg;
                if (lane == ol) sinv[jrow] = si;     // static reg access, one LDS store
                if (lane == jrow) a0[j] = dg;
                else if (lane > jrow) a0[j] *= si;
                if (lane + 64 == jrow) a1[j] = dg;
                else if (lane + 64 > jrow) a1[j] *= si;
#pragma unroll
                for (int c = j + 1; c < 8; ++c) {
                    float ls  = sc ? a1[j] : a0[j];
                    float ljc = __shfl(ls, (j0 + c) & 63);   // L[j0+c][j] (scaled)
                    if (lane > jrow)      a0[c] = fmaf(-a0[j], ljc, a0[c]);
                    if (lane + 64 > jrow) a1[c] = fmaf(-a1[j], ljc, a1[c]);
                }
            }
#pragma unroll
            for (int c = 0; c < 8; ++c) {
                if (lane >= j0 + c)      As[lane][j0 + c]      = a0[c];
                if (lane + 64 >= j0 + c) As[lane + 64][j0 + c] = a1[c];
            }
        }
        __syncthreads();
        // trailing rank-8 update of columns right of the panel
        if (p < 15) {
            int r = tid & 127;
            int q = tid >> 7;
            int nq = nthr >> 7;
            float a[8];
#pragma unroll
            for (int t = 0; t < 8; ++t) a[t] = As[r][j0 + t];
            for (int c = j0 + 8 + q; c < 128; c += nq) {
                if (r >= c) {
                    float s = As[r][c];
#pragma unroll
                    for (int t = 0; t < 8; ++t) s -= a[t] * As[c][j0 + t];
                    As[r][c] = s;
                }
            }
        }
        __syncthreads();
    }

    // W11 = inv(L11): thread c (<128) owns column c; X[t][c] stored at As[c][t] (t>c)
    if (tid < 128) {
        int c = tid;
        for (int rb = 0; rb < 16; ++rb) {
            int r0b = rb * 8;
            if (c >= r0b + 8) continue;
            float s[8];
#pragma unroll
            for (int i = 0; i < 8; ++i) s[i] = 0.0f;
            for (int t = 0; t < r0b; ++t) {
                if (t >= c) {
                    float xt = (t == c) ? sinv[c] : As[c][t];
#pragma unroll
                    for (int i = 0; i < 8; ++i) s[i] += As[r0b + i][t] * xt;
                }
            }
            float xloc[8];
#pragma unroll
            for (int i = 0; i < 8; ++i) {
                int rr = r0b + i;
                float v = 0.0f;
                if (rr >= c) {
                    v = ((rr == c) ? 1.0f : 0.0f) - s[i];
#pragma unroll
                    for (int t2 = 0; t2 < i; ++t2) {
                        int tt = r0b + t2;
                        if (tt >= c) v -= As[rr][tt] * xloc[t2];
                    }
                    v *= sinv[rr];
                    if (rr > c) As[c][rr] = v;
                }
                xloc[i] = v;
            }
        }
    }
    __syncthreads();
    for (int idx = tid; idx < BS * BS; idx += nthr) {
        int rr = idx >> 7, cc = idx & 127;
        if (rr >= cc)
            Wf[(size_t)(r0 + rr) * M_N + r0 + cc] = (rr == cc) ? sinv[rr] : As[cc][rr];
    }
}

// ---------------- standalone Cholesky diag block kb=0 (grid padded to 64) -------------
__global__ __launch_bounds__(512) void kw_diag(float* __restrict__ Kf,
                                               float* __restrict__ Wf, int kb) {
    if (blockIdx.x) return;   // grid padding (tiny-grid stall mitigation)
    __shared__ float As[128][129];
    __shared__ float sinv[128];
    int tid = threadIdx.x;
    int r0 = kb * BS;
    for (int idx = tid; idx < BS * BS; idx += 512) {
        int rr = idx >> 7, cc = idx & 127;
        As[rr][cc] = Kf[(size_t)(r0 + rr) * M_N + r0 + cc];
    }
    __syncthreads();
    d_diag_fast(As, sinv, Wf, r0, tid, 512);
}

// ---------------- strip: S(64x128) = A21[row0..] * W11^T (fp32, into LDS) -------------
static __device__ void d_strip(const float* __restrict__ Kf, const float* __restrict__ Wf,
                               int cb, int row0, float (*S)[129],
                               float (*Ast)[17], float (*Wst)[128], int tid) {
    int c = tid & 127, q = tid >> 7;
    float acc[32];
#pragma unroll
    for (int i = 0; i < 32; ++i) acc[i] = 0.0f;
    for (int tc = 0; tc < 8; ++tc) {
        int tb = tc * 16;
        __syncthreads();
        for (int idx = tid; idx < 64 * 16; idx += 256) {
            int rr = idx >> 4, tt = idx & 15;
            Ast[rr][tt] = Kf[(size_t)(row0 + rr) * M_N + cb + tb + tt];
        }
        for (int idx = tid; idx < 128 * 16; idx += 256) {
            int cc = idx >> 4, tt = idx & 15;
            Wst[tt][cc] = (tb + tt <= cc) ? Wf[(size_t)(cb + cc) * M_N + cb + tb + tt] : 0.0f;
        }
        __syncthreads();
#pragma unroll
        for (int t = 0; t < 16; ++t) {
            float w = Wst[t][c];
#pragma unroll
            for (int i = 0; i < 32; ++i) acc[i] += Ast[q * 32 + i][t] * w;
        }
    }
    __syncthreads();
#pragma unroll
    for (int i = 0; i < 32; ++i) S[q * 32 + i][c] = acc[i];
}

// ---------------- step kb: trailing update + NEXT diag fused into block 0 -------------
__global__ __launch_bounds__(256) void kw_step(float* __restrict__ Kf,
                                               float* __restrict__ Wf,
                                               float* __restrict__ Lf, int kb) {
    __shared__ float SA[64][129];
    __shared__ float SB[64][129];
    __shared__ float Ast[64][17];
    __shared__ float Wst[16][128];
    __shared__ float As[128][129];
    __shared__ float sinv[128];
    int tid = threadIdx.x;
    int base = (kb + 1) * BS;
    int cb = kb * BS;
    int tx = tid & 15, ty = tid >> 4;
    int nt = (NBK - 1 - kb) * 2;
    int ntile = nt * (nt + 1) / 2;

    if (blockIdx.x == 0) {
        d_strip(Kf, Wf, cb, base, SA, Ast, Wst, tid);
        d_strip(Kf, Wf, cb, base + 64, SB, Ast, Wst, tid);
        __syncthreads();
#pragma unroll
        for (int qq = 0; qq < 3; ++qq) {
            int qy = (qq == 0) ? 0 : 1;
            int qx = (qq == 2) ? 1 : 0;
            float (*Sy)[129] = qy ? SB : SA;
            float (*Sx)[129] = qx ? SB : SA;
            float acc[4][4];
#pragma unroll
            for (int i = 0; i < 4; ++i)
#pragma unroll
                for (int j = 0; j < 4; ++j) acc[i][j] = 0.0f;
            for (int t = 0; t < 128; ++t) {
                float a[4], b[4];
#pragma unroll
                for (int i = 0; i < 4; ++i) a[i] = Sy[ty * 4 + i][t];
#pragma unroll
                for (int j = 0; j < 4; ++j) b[j] = Sx[tx * 4 + j][t];
#pragma unroll
                for (int i = 0; i < 4; ++i)
#pragma unroll
                    for (int j = 0; j < 4; ++j) acc[i][j] = fmaf(a[i], b[j], acc[i][j]);
            }
#pragma unroll
            for (int i = 0; i < 4; ++i)
#pragma unroll
                for (int j = 0; j < 4; ++j)
                    As[qy * 64 + ty * 4 + i][qx * 64 + tx * 4 + j] =
                        Kf[(size_t)(base + qy * 64 + ty * 4 + i) * M_N +
                           base + qx * 64 + tx * 4 + j] - acc[i][j];
        }
        for (int idx = tid; idx < 64 * 128; idx += 256) {
            int rr = idx >> 7, cc = idx & 127;
            Lf[(size_t)(base + rr) * M_N + cb + cc]      = SA[rr][cc];
            Lf[(size_t)(base + 64 + rr) * M_N + cb + cc] = SB[rr][cc];
        }
        __syncthreads();
        d_diag_fast(As, sinv, Wf, base, tid, 256);
    } else {
        int vp = blockIdx.x + 2;
        if (vp >= ntile) return;   // grid padding
        int by = 0;
        while ((by + 1) * (by + 2) / 2 <= vp) ++by;
        int bx = vp - by * (by + 1) / 2;
        int gr0 = base + by * 64, gc0 = base + bx * 64;
        d_strip(Kf, Wf, cb, gr0, SA, Ast, Wst, tid);
        if (bx != by) d_strip(Kf, Wf, cb, gc0, SB, Ast, Wst, tid);
        float (*PB)[129] = (bx == by) ? SA : SB;
        __syncthreads();
        float acc[4][4];
#pragma unroll
        for (int i = 0; i < 4; ++i)
#pragma unroll
            for (int j = 0; j < 4; ++j) acc[i][j] = 0.0f;
        for (int t = 0; t < 128; ++t) {
            float a[4], b[4];
#pragma unroll
            for (int i = 0; i < 4; ++i) a[i] = SA[ty * 4 + i][t];
#pragma unroll
            for (int j = 0; j < 4; ++j) b[j] = PB[tx * 4 + j][t];
#pragma unroll
            for (int i = 0; i < 4; ++i)
#pragma unroll
                for (int j = 0; j < 4; ++j) acc[i][j] = fmaf(a[i], b[j], acc[i][j]);
        }
#pragma unroll
        for (int i = 0; i < 4; ++i)
#pragma unroll
            for (int j = 0; j < 4; ++j)
                Kf[(size_t)(gr0 + ty * 4 + i) * M_N + gc0 + tx * 4 + j] -= acc[i][j];
        if (by == bx) {
            for (int idx = tid; idx < 64 * 128; idx += 256)
                Lf[(size_t)(gr0 + (idx >> 7)) * M_N + cb + (idx & 127)] =
                    SA[idx >> 7][idx & 127];
        }
    }
}

// ---------------- trtri: single launch, fp32 (verified r7) ----------------
__global__ __launch_bounds__(512) void kw_trtri(const float* __restrict__ Lf,
                                                float* __restrict__ Wf) {
    __shared__ float Ls[128][33];
    __shared__ float Ws[32][33];
    __shared__ float Whist[6][128][33];
    __shared__ float Ps[128][33];
    int j  = blockIdx.y;
    int ct = blockIdx.x;
    int c0 = j * BS + ct * 32;
    int tid = threadIdx.x;
    int rq = tid >> 2, cq = tid & 3;

    for (int i = j + 1; i < 8; ++i) {
        float acc[8];
#pragma unroll
        for (int c = 0; c < 8; ++c) acc[c] = 0.0f;
        for (int t = j; t < i; ++t) {
            for (int ch = 0; ch < 4; ++ch) {
                int tb = t * BS + ch * 32;
                __syncthreads();
                for (int idx = tid; idx < 128 * 32; idx += 512) {
                    int rr = idx >> 5, tt = idx & 31;
                    Ls[rr][tt] = Lf[(size_t)(i * BS + rr) * M_N + tb + tt];
                }
                if (t == j) {
                    for (int idx = tid; idx < 32 * 32; idx += 512) {
                        int tt = idx >> 5, cc = idx & 31;
                        int gr = tb + tt, gc = c0 + cc;
                        Ws[tt][cc] = (gr >= gc) ? Wf[(size_t)gr * M_N + gc] : 0.0f;
                    }
                }
                __syncthreads();
                if (t == j) {
#pragma unroll
                    for (int tt = 0; tt < 32; ++tt) {
                        float l = Ls[rq][tt];
#pragma unroll
                        for (int c = 0; c < 8; ++c)
                            acc[c] = fmaf(l, Ws[tt][cq * 8 + c], acc[c]);
                    }
                } else {
                    const float (*Wh)[33] = Whist[t - j - 1];
#pragma unroll
                    for (int tt = 0; tt < 32; ++tt) {
                        float l = Ls[rq][tt];
#pragma unroll
                        for (int c = 0; c < 8; ++c)
                            acc[c] = fmaf(l, Wh[ch * 32 + tt][cq * 8 + c], acc[c]);
                    }
                }
            }
        }
        __syncthreads();
#pragma unroll
        for (int c = 0; c < 8; ++c) Ps[rq][cq * 8 + c] = acc[c];
        float a2[8];
#pragma unroll
        for (int c = 0; c < 8; ++c) a2[c] = 0.0f;
        for (int ch = 0; ch < 4; ++ch) {
            __syncthreads();
            for (int idx = tid; idx < 128 * 32; idx += 512) {
                int rr = idx >> 5, tt = idx & 31;
                Ls[rr][tt] = (rr >= ch * 32 + tt)
                           ? Wf[(size_t)(i * BS + rr) * M_N + i * BS + ch * 32 + tt] : 0.0f;
            }
            __syncthreads();
#pragma unroll
            for (int tt = 0; tt < 32; ++tt) {
                float l = Ls[rq][tt];
#pragma unroll
                for (int c = 0; c < 8; ++c)
                    a2[c] = fmaf(l, Ps[ch * 32 + tt][cq * 8 + c], a2[c]);
            }
        }
        __syncthreads();
#pragma unroll
        for (int c = 0; c < 8; ++c) {
            float v = -a2[c];
            Wf[(size_t)(i * BS + rq) * M_N + c0 + cq * 8 + c] = v;
            if (i < 7) Whist[i - j - 1][rq][cq * 8 + c] = v;
        }
        __syncthreads();
    }
}

// ---------------- pack W (fp32) into MFMA B-fragment order, fp16 hi/lo ----------------
__global__ void kw_pack(const float* __restrict__ Wf, _Float16* __restrict__ Wph,
                        _Float16* __restrict__ Wpl) {
    int T = blockIdx.x * 256 + threadIdx.x;
    int lane = T & 63, fid = T >> 6;
    int jn = fid & 63, kik = fid >> 6;
    int ki = kik & 3, kc = kik >> 2;
    int j  = jn * 16 + (lane & 15);
    int kb = kc * 128 + ki * 32 + (lane >> 4) * 8;
    f16x8 h, lo;
#pragma unroll
    for (int e = 0; e < 8; ++e) {
        int k = kb + e;
        float v = (k <= j) ? Wf[(size_t)j * M_N + k] : 0.0f;
        _Float16 hh = (_Float16)v;
        h[e]  = hh;
        lo[e] = (_Float16)(v - (float)hh);
    }
    size_t off = (size_t)fid * 512 + lane * 8;
    *(f16x8*)(Wph + off) = h;
    *(f16x8*)(Wpl + off) = lo;
}

// ---------------- main fused MFMA kernel: 64 rows x 1024 cols, FULL tile in LDS -------
__global__ __launch_bounds__(512) void k_mm(const float* __restrict__ x_star,
                                            const float* __restrict__ pf,
                                            const float* __restrict__ Zst,
                                            const _Float16* __restrict__ Wph,
                                            const _Float16* __restrict__ Wpl,
                                            float* __restrict__ out, int Bq) {
    __shared__ __align__(16) char kls[64 * 2048];   // [row][1024 fp16], 16B-slot swizzled
    __shared__ float red_l[64];
    int tid  = threadIdx.x;
    int slab = blockIdx.x;
    int w = tid >> 6, lane = tid & 63;
    int lrow = lane & 15, kgrp = lane >> 4;

    int scc = tid & 15, srow0 = tid >> 4;
    int q0 = slab * 64 + srow0;
    int q1 = q0 + 32;
    int qa = (q0 < Bq) ? q0 : (Bq - 1);
    int qb = (q1 < Bq) ? q1 : (Bq - 1);
    float xa0 = x_star[(size_t)qa * 5 + 0] * pf[0];
    float xa1 = x_star[(size_t)qa * 5 + 1] * pf[1];
    float xa2 = x_star[(size_t)qa * 5 + 2] * pf[2];
    float xa3 = x_star[(size_t)qa * 5 + 3] * pf[3];
    float xa4 = x_star[(size_t)qa * 5 + 4] * pf[4];
    float xb0 = x_star[(size_t)qb * 5 + 0] * pf[0];
    float xb1 = x_star[(size_t)qb * 5 + 1] * pf[1];
    float xb2 = x_star[(size_t)qb * 5 + 2] * pf[2];
    float xb3 = x_star[(size_t)qb * 5 + 3] * pf[3];
    float xb4 = x_star[(size_t)qb * 5 + 4] * pf[4];
    float pv = pf[5];
    if (tid < 64) red_l[tid] = 0.0f;

    int swz = (srow0 & 15) << 4;
    for (int kc = 0; kc < 8; ++kc) {
        f16x8 h0, h1;
#pragma unroll
        for (int bb = 0; bb < 2; ++bb) {
            int lb = kc * 128 + scc * 8 + bb * 4;
            float z0[4], z1[4], z2[4], z3[4], z4[4];
            *(float4*)z0 = *(const float4*)&Zst[lb];
            *(float4*)z1 = *(const float4*)&Zst[M_N + lb];
            *(float4*)z2 = *(const float4*)&Zst[2 * M_N + lb];
            *(float4*)z3 = *(const float4*)&Zst[3 * M_N + lb];
            *(float4*)z4 = *(const float4*)&Zst[4 * M_N + lb];
#pragma unroll
            for (int e = 0; e < 4; ++e) {
                float dx0 = xa0 - z0[e], dx1 = xa1 - z1[e], dx2 = xa2 - z2[e],
                      dx3 = xa3 - z3[e], dx4 = xa4 - z4[e];
                float d2 = dx0 * dx0 + dx1 * dx1 + dx2 * dx2 + dx3 * dx3 + dx4 * dx4;
                float dd = d2 + 1e-8f;
                float dist = sqrtf(dd);
                float sv = 2.23606798f * dist;
                h0[bb * 4 + e] = (_Float16)(pv * (1.0f + sv + 1.66666667f * dd) * __expf(-sv));
                float ex0 = xb0 - z0[e], ex1 = xb1 - z1[e], ex2 = xb2 - z2[e],
                      ex3 = xb3 - z3[e], ex4 = xb4 - z4[e];
                float e2 = ex0 * ex0 + ex1 * ex1 + ex2 * ex2 + ex3 * ex3 + ex4 * ex4;
                float ee = e2 + 1e-8f;
                float edist = sqrtf(ee);
                float esv = 2.23606798f * edist;
                h1[bb * 4 + e] = (_Float16)(pv * (1.0f + esv + 1.66666667f * ee) * __expf(-esv));
            }
        }
        int cb = kc * 256 + scc * 16;
        *(f16x8*)(&kls[srow0 * 2048 + (cb ^ swz)]) = h0;
        *(f16x8*)(&kls[(srow0 + 32) * 2048 + (cb ^ swz)]) = h1;
    }
    __syncthreads();

    for (int jg = 0; jg < 4; ++jg) {
        f32x4 acc[4][2];
#pragma unroll
        for (int mi = 0; mi < 4; ++mi)
#pragma unroll
            for (int nj = 0; nj < 2; ++nj) acc[mi][nj] = (f32x4)(0.0f);

        int jng_hi = jg * 16 + 8 + ((w + 1) & 7);
        int jmax_w = jng_hi * 16 + 15;

        for (int kt = 0; kt < 32; ++kt) {
            int kmin = kt * 32;
            if (kmin > jmax_w) break;
            f16x8 A_[4];
#pragma unroll
            for (int mi = 0; mi < 4; ++mi) {
                int row = mi * 16 + lrow;
                int cb  = kt * 64 + kgrp * 16;
                A_[mi] = *(const f16x8*)(&kls[row * 2048 + (cb ^ ((row & 15) << 4))]);
            }
#pragma unroll
            for (int nj = 0; nj < 2; ++nj) {
                int jng = jg * 16 + nj * 8 + ((w + nj) & 7);
                if (kmin > jng * 16 + 15) continue;
                size_t fo = ((size_t)(kt * 64 + jng)) * 512 + lane * 8;
                f16x8 Bh = *(const f16x8*)(Wph + fo);
                f16x8 Bl = *(const f16x8*)(Wpl + fo);
#pragma unroll
                for (int mi = 0; mi < 4; ++mi) {
                    acc[mi][nj] = __builtin_amdgcn_mfma_f32_16x16x32_f16(A_[mi], Bh, acc[mi][nj], 0, 0, 0);
                    acc[mi][nj] = __builtin_amdgcn_mfma_f32_16x16x32_f16(A_[mi], Bl, acc[mi][nj], 0, 0, 0);
                }
            }
        }
#pragma unroll
        for (int mi = 0; mi < 4; ++mi) {
#pragma unroll
            for (int q = 0; q < 4; ++q) {
                float s = 0.0f;
#pragma unroll
                for (int nj = 0; nj < 2; ++nj) s = fmaf(acc[mi][nj][q], acc[mi][nj][q], s);
                s += __shfl_xor(s, 1);
                s += __shfl_xor(s, 2);
                s += __shfl_xor(s, 4);
                s += __shfl_xor(s, 8);
                if (lrow == 0) atomicAdd(&red_l[mi * 16 + kgrp * 4 + q], s);
            }
        }
    }
    __syncthreads();
    if (tid < 64) {
        int b = slab * 64 + tid;
        if (b < Bq) out[b] = sqrtf(fmaxf(pv - red_l[tid], 1e-6f));
    }
}

extern "C" void kernel_launch(void* const* d_in, const int* in_sizes, int n_in,
                              void* d_out, int out_size, void* d_ws, size_t ws_size,
                              hipStream_t stream) {
    const float* x_star  = (const float*)d_in[0];
    const float* log_ls  = (const float*)d_in[1];
    const float* log_var = (const float*)d_in[2];
    const float* Z_raw   = (const float*)d_in[3];
    float* out = (float*)d_out;
    int Bq = in_sizes[0] / 5;

    char* ws = (char*)d_ws;
    float*     Kf  = (float*)(ws + OFF_KF);
    float*     Lf  = (float*)(ws + OFF_LF);
    float*     Wf  = (float*)(ws + OFF_WF);
    _Float16*  Wph = (_Float16*)(ws + OFF_WPH);
    _Float16*  Wpl = (_Float16*)(ws + OFF_WPL);
    float*     pf  = (float*)(ws + OFF_PF);
    float*     Zst = (float*)(ws + OFF_ZT);

    k_build<<<4096, 256, 0, stream>>>(log_ls, log_var, Z_raw, Kf, pf, Zst);
    kw_diag<<<64, 512, 0, stream>>>(Kf, Wf, 0);
    for (int kb = 0; kb < NBK - 1; ++kb) {
        int nt = (NBK - 1 - kb) * 2;
        int grid = nt * (nt + 1) / 2 - 2;
        if (grid < 64) grid = 64;                // tiny-grid stall mitigation
        kw_step<<<grid, 256, 0, stream>>>(Kf, Wf, Lf, kb);
    }
    kw_trtri<<<dim3(4, 7), 512, 0, stream>>>(Lf, Wf);
    kw_pack<<<512, 256, 0, stream>>>(Wf, Wph, Wpl);

    int slabs = (Bq + 63) / 64;
    k_mm<<<slabs, 512, 0, stream>>>(x_star, pf, Zst, Wph, Wpl, out, Bq);
}

// Round 15
// 3355.719 us; speedup vs baseline: 1.2740x; 1.2740x over previous
//
#include <hip/hip_runtime.h>
#include <math.h>

// Sizes fixed by the problem.
#define B_TOT 131072
#define M_N   1024
#define BS    128      // Cholesky block size
#define NBK   8        // M_N / BS

typedef float    f32x4 __attribute__((ext_vector_type(4)));
typedef _Float16 f16x8 __attribute__((ext_vector_type(8)));

// Workspace layout (bytes). Total ~17 MB.
enum : size_t {
    OFF_KF  = 0,                          // fp32 K (Schur-updated)  4 MB
    OFF_LF  = (size_t)4 << 20,            // fp32 L off-diag strips  4 MB
    OFF_WF  = (size_t)8 << 20,            // fp32 W = L^-1 (lower)   4 MB
    OFF_WPH = (size_t)12 << 20,           // fp16 W packed hi        2 MB
    OFF_WPL = (size_t)14 << 20,           // fp16 W packed lo        2 MB
    OFF_PF  = (size_t)16 << 20,           // fp32 params (6)
    OFF_ZT  = ((size_t)16 << 20) + 256,   // fp32 Zs_t [5][1024]     20 KB
};

__device__ __constant__ float c_zscale[5] = {0.15f, 0.1f, 0.05f, 800.0f, 20.0f};
__device__ __constant__ float c_zshift[5] = {0.0f, 0.0f, 0.0f, 600.0f, 5.0f};

// ---------------- fused: params + Zst + K = matern52 + jitter (fp32) ----------------
__global__ __launch_bounds__(256) void k_build(const float* __restrict__ log_ls,
                                               const float* __restrict__ log_var,
                                               const float* __restrict__ Zraw,
                                               float* __restrict__ Kf,
                                               float* __restrict__ pf,
                                               float* __restrict__ Zst) {
    __shared__ float ps[6];
    __shared__ float zsi[5];
    int tid = threadIdx.x;
    if (tid < 5) ps[tid] = 1.0f / (__expf(log_ls[tid]) + 1e-8f);
    if (tid == 5) ps[5] = __expf(log_var[0]);
    __syncthreads();
    int i = blockIdx.x >> 2;
    int j = (blockIdx.x & 3) * 256 + tid;
    if (tid < 5) zsi[tid] = (Zraw[i * 5 + tid] * c_zscale[tid] + c_zshift[tid]) * ps[tid];
    __syncthreads();
    float d2 = 0.0f;
#pragma unroll
    for (int d = 0; d < 5; ++d) {
        float zj = (Zraw[j * 5 + d] * c_zscale[d] + c_zshift[d]) * ps[d];
        float df = zsi[d] - zj;
        d2 += df * df;
    }
    float dd = d2 + 1e-8f;
    float dist = sqrtf(dd);
    float s = 2.23606798f * dist;
    float v = ps[5] * (1.0f + s + 1.66666667f * dd) * __expf(-s);
    if (i == j) v += 1e-4f;
    Kf[(size_t)i * M_N + j] = v;
    if (blockIdx.x < 4) {
        int m = blockIdx.x * 256 + tid;
#pragma unroll
        for (int d = 0; d < 5; ++d)
            Zst[d * M_N + m] = (Zraw[m * 5 + d] * c_zscale[d] + c_zshift[d]) * ps[d];
    }
    if (blockIdx.x == 4 && tid < 6) pf[tid] = ps[tid];
}

// ---------------- standalone Cholesky diag block kb=0 (r12-verified) ----------------
__global__ __launch_bounds__(512) void kw_diag(float* __restrict__ Kf,
                                               float* __restrict__ Wf, int kb) {
    if (blockIdx.x) return;   // grid padding (tiny-grid stall mitigation)
    __shared__ float As[128][129];
    __shared__ float sinv[128];
    int tid = threadIdx.x;
    int r0 = kb * BS;
    for (int idx = tid; idx < BS * BS; idx += 512) {
        int rr = idx >> 7, cc = idx & 127;
        As[rr][cc] = Kf[(size_t)(r0 + rr) * M_N + r0 + cc];
    }
    __syncthreads();

    int r = tid & 127, q = tid >> 7;
    for (int p = 0; p < 16; ++p) {
        int j0 = p * 8;
        for (int j = j0; j < j0 + 8; ++j) {
            if (tid == j) {
                float d = sqrtf(As[j][j]);
                As[j][j] = d;
                sinv[j] = 1.0f / d;
            }
            __syncthreads();
            float arj = 0.0f;
            if (q == 0 && r > j) {
                arj = As[r][j] * sinv[j];
                As[r][j] = arj;
            }
            __syncthreads();
            if (q == 0 && r > j) {
#pragma unroll
                for (int c = j + 1; c < j0 + 8; ++c)
                    As[r][c] -= arj * As[c][j];
            }
        }
        __syncthreads();
        if (p < 15) {
            float a[8];
#pragma unroll
            for (int t = 0; t < 8; ++t) a[t] = As[r][j0 + t];
            for (int c = j0 + 8 + q; c < 128; c += 4) {
                if (r >= c) {
                    float s = As[r][c];
#pragma unroll
                    for (int t = 0; t < 8; ++t) s -= a[t] * As[c][j0 + t];
                    As[r][c] = s;
                }
            }
        }
        __syncthreads();
    }

    if (tid < 128) {
        int c = tid;
        for (int rb = 0; rb < 16; ++rb) {
            int r0b = rb * 8;
            if (c >= r0b + 8) continue;
            float s[8];
#pragma unroll
            for (int i = 0; i < 8; ++i) s[i] = 0.0f;
            for (int t = 0; t < r0b; ++t) {
                if (t >= c) {
                    float xt = (t == c) ? sinv[c] : As[c][t];
#pragma unroll
                    for (int i = 0; i < 8; ++i) s[i] += As[r0b + i][t] * xt;
                }
            }
            float xloc[8];
#pragma unroll
            for (int i = 0; i < 8; ++i) {
                int rr = r0b + i;
                float v = 0.0f;
                if (rr >= c) {
                    v = ((rr == c) ? 1.0f : 0.0f) - s[i];
#pragma unroll
                    for (int t2 = 0; t2 < i; ++t2) {
                        int tt = r0b + t2;
                        if (tt >= c) v -= As[rr][tt] * xloc[t2];
                    }
                    v *= sinv[rr];
                    if (rr > c) As[c][rr] = v;
                }
                xloc[i] = v;
            }
        }
    }
    __syncthreads();
    for (int idx = tid; idx < BS * BS; idx += 512) {
        int rr = idx >> 7, cc = idx & 127;
        if (rr >= cc)
            Wf[(size_t)(r0 + rr) * M_N + r0 + cc] = (rr == cc) ? sinv[rr] : As[cc][rr];
    }
}

// ---------------- strip: S(64x128) = A21[row0..] * W11^T (fp32, into LDS) -------------
static __device__ void d_strip(const float* __restrict__ Kf, const float* __restrict__ Wf,
                               int cb, int row0, float (*S)[129],
                               float (*Ast)[17], float (*Wst)[128], int tid) {
    int c = tid & 127, q = tid >> 7;
    float acc[32];
#pragma unroll
    for (int i = 0; i < 32; ++i) acc[i] = 0.0f;
    for (int tc = 0; tc < 8; ++tc) {
        int tb = tc * 16;
        __syncthreads();
        for (int idx = tid; idx < 64 * 16; idx += 256) {
            int rr = idx >> 4, tt = idx & 15;
            Ast[rr][tt] = Kf[(size_t)(row0 + rr) * M_N + cb + tb + tt];
        }
        for (int idx = tid; idx < 128 * 16; idx += 256) {
            int cc = idx >> 4, tt = idx & 15;
            Wst[tt][cc] = (tb + tt <= cc) ? Wf[(size_t)(cb + cc) * M_N + cb + tb + tt] : 0.0f;
        }
        __syncthreads();
#pragma unroll
        for (int t = 0; t < 16; ++t) {
            float w = Wst[t][c];
#pragma unroll
            for (int i = 0; i < 32; ++i) acc[i] += Ast[q * 32 + i][t] * w;
        }
    }
    __syncthreads();
#pragma unroll
    for (int i = 0; i < 32; ++i) S[q * 32 + i][c] = acc[i];
}

// ---------------- diag factor + inverse, 256 threads (r12-verified) ----------------
static __device__ void d_diag256(float (*As)[129], float* sinv,
                                 float* __restrict__ Wf, int r0, int tid) {
    int r = tid & 127, half = tid >> 7;
    for (int p = 0; p < 16; ++p) {
        int j0 = p * 8;
        for (int j = j0; j < j0 + 8; ++j) {
            if (tid == j) {
                float d = sqrtf(As[j][j]);
                As[j][j] = d;
                sinv[j] = 1.0f / d;
            }
            __syncthreads();
            float arj = 0.0f;
            if (half == 0 && r > j) {
                arj = As[r][j] * sinv[j];
                As[r][j] = arj;
            }
            __syncthreads();
            if (half == 0 && r > j) {
#pragma unroll
                for (int c = j + 1; c < j0 + 8; ++c)
                    As[r][c] -= arj * As[c][j];
            }
        }
        __syncthreads();
        if (p < 15) {
            float a[8];
#pragma unroll
            for (int t = 0; t < 8; ++t) a[t] = As[r][j0 + t];
            for (int c = j0 + 8 + half; c < 128; c += 2) {
                if (r >= c) {
                    float s = As[r][c];
#pragma unroll
                    for (int t = 0; t < 8; ++t) s -= a[t] * As[c][j0 + t];
                    As[r][c] = s;
                }
            }
        }
        __syncthreads();
    }
    if (tid < 128) {
        int c = tid;
        for (int rb = 0; rb < 16; ++rb) {
            int r0b = rb * 8;
            if (c >= r0b + 8) continue;
            float s[8];
#pragma unroll
            for (int i = 0; i < 8; ++i) s[i] = 0.0f;
            for (int t = 0; t < r0b; ++t) {
                if (t >= c) {
                    float xt = (t == c) ? sinv[c] : As[c][t];
#pragma unroll
                    for (int i = 0; i < 8; ++i) s[i] += As[r0b + i][t] * xt;
                }
            }
            float xloc[8];
#pragma unroll
            for (int i = 0; i < 8; ++i) {
                int rr = r0b + i;
                float v = 0.0f;
                if (rr >= c) {
                    v = ((rr == c) ? 1.0f : 0.0f) - s[i];
#pragma unroll
                    for (int t2 = 0; t2 < i; ++t2) {
                        int tt = r0b + t2;
                        if (tt >= c) v -= As[rr][tt] * xloc[t2];
                    }
                    v *= sinv[rr];
                    if (rr > c) As[c][rr] = v;
                }
                xloc[i] = v;
            }
        }
    }
    __syncthreads();
    for (int idx = tid; idx < BS * BS; idx += 256) {
        int rr = idx >> 7, cc = idx & 127;
        if (rr >= cc)
            Wf[(size_t)(r0 + rr) * M_N + r0 + cc] = (rr == cc) ? sinv[rr] : As[cc][rr];
    }
}

// ---------------- step kb: trailing update + NEXT diag fused into block 0 -------------
__global__ __launch_bounds__(256) void kw_step(float* __restrict__ Kf,
                                               float* __restrict__ Wf,
                                               float* __restrict__ Lf, int kb) {
    __shared__ float SA[64][129];
    __shared__ float SB[64][129];
    __shared__ float Ast[64][17];
    __shared__ float Wst[16][128];
    __shared__ float As[128][129];
    __shared__ float sinv[128];
    int tid = threadIdx.x;
    int base = (kb + 1) * BS;
    int cb = kb * BS;
    int tx = tid & 15, ty = tid >> 4;
    int nt = (NBK - 1 - kb) * 2;
    int ntile = nt * (nt + 1) / 2;

    if (blockIdx.x == 0) {
        d_strip(Kf, Wf, cb, base, SA, Ast, Wst, tid);
        d_strip(Kf, Wf, cb, base + 64, SB, Ast, Wst, tid);
        __syncthreads();
#pragma unroll
        for (int qq = 0; qq < 3; ++qq) {
            int qy = (qq == 0) ? 0 : 1;
            int qx = (qq == 2) ? 1 : 0;
            float (*Sy)[129] = qy ? SB : SA;
            float (*Sx)[129] = qx ? SB : SA;
            float acc[4][4];
#pragma unroll
            for (int i = 0; i < 4; ++i)
#pragma unroll
                for (int j = 0; j < 4; ++j) acc[i][j] = 0.0f;
            for (int t = 0; t < 128; ++t) {
                float a[4], b[4];
#pragma unroll
                for (int i = 0; i < 4; ++i) a[i] = Sy[ty * 4 + i][t];
#pragma unroll
                for (int j = 0; j < 4; ++j) b[j] = Sx[tx * 4 + j][t];
#pragma unroll
                for (int i = 0; i < 4; ++i)
#pragma unroll
                    for (int j = 0; j < 4; ++j) acc[i][j] = fmaf(a[i], b[j], acc[i][j]);
            }
#pragma unroll
            for (int i = 0; i < 4; ++i)
#pragma unroll
                for (int j = 0; j < 4; ++j)
                    As[qy * 64 + ty * 4 + i][qx * 64 + tx * 4 + j] =
                        Kf[(size_t)(base + qy * 64 + ty * 4 + i) * M_N +
                           base + qx * 64 + tx * 4 + j] - acc[i][j];
        }
        for (int idx = tid; idx < 64 * 128; idx += 256) {
            int rr = idx >> 7, cc = idx & 127;
            Lf[(size_t)(base + rr) * M_N + cb + cc]      = SA[rr][cc];
            Lf[(size_t)(base + 64 + rr) * M_N + cb + cc] = SB[rr][cc];
        }
        __syncthreads();
        d_diag256(As, sinv, Wf, base, tid);
    } else {
        int vp = blockIdx.x + 2;
        if (vp >= ntile) return;   // grid padding
        int by = 0;
        while ((by + 1) * (by + 2) / 2 <= vp) ++by;
        int bx = vp - by * (by + 1) / 2;
        int gr0 = base + by * 64, gc0 = base + bx * 64;
        d_strip(Kf, Wf, cb, gr0, SA, Ast, Wst, tid);
        if (bx != by) d_strip(Kf, Wf, cb, gc0, SB, Ast, Wst, tid);
        float (*PB)[129] = (bx == by) ? SA : SB;
        __syncthreads();
        float acc[4][4];
#pragma unroll
        for (int i = 0; i < 4; ++i)
#pragma unroll
            for (int j = 0; j < 4; ++j) acc[i][j] = 0.0f;
        for (int t = 0; t < 128; ++t) {
            float a[4], b[4];
#pragma unroll
            for (int i = 0; i < 4; ++i) a[i] = SA[ty * 4 + i][t];
#pragma unroll
            for (int j = 0; j < 4; ++j) b[j] = PB[tx * 4 + j][t];
#pragma unroll
            for (int i = 0; i < 4; ++i)
#pragma unroll
                for (int j = 0; j < 4; ++j) acc[i][j] = fmaf(a[i], b[j], acc[i][j]);
        }
#pragma unroll
        for (int i = 0; i < 4; ++i)
#pragma unroll
            for (int j = 0; j < 4; ++j)
                Kf[(size_t)(gr0 + ty * 4 + i) * M_N + gc0 + tx * 4 + j] -= acc[i][j];
        if (by == bx) {
            for (int idx = tid; idx < 64 * 128; idx += 256)
                Lf[(size_t)(gr0 + (idx >> 7)) * M_N + cb + (idx & 127)] =
                    SA[idx >> 7][idx & 127];
        }
    }
}

// ---------------- trtri: single launch, fp32 (verified r7) ----------------
__global__ __launch_bounds__(512) void kw_trtri(const float* __restrict__ Lf,
                                                float* __restrict__ Wf) {
    __shared__ float Ls[128][33];
    __shared__ float Ws[32][33];
    __shared__ float Whist[6][128][33];
    __shared__ float Ps[128][33];
    int j  = blockIdx.y;
    int ct = blockIdx.x;
    int c0 = j * BS + ct * 32;
    int tid = threadIdx.x;
    int rq = tid >> 2, cq = tid & 3;

    for (int i = j + 1; i < 8; ++i) {
        float acc[8];
#pragma unroll
        for (int c = 0; c < 8; ++c) acc[c] = 0.0f;
        for (int t = j; t < i; ++t) {
            for (int ch = 0; ch < 4; ++ch) {
                int tb = t * BS + ch * 32;
                __syncthreads();
                for (int idx = tid; idx < 128 * 32; idx += 512) {
                    int rr = idx >> 5, tt = idx & 31;
                    Ls[rr][tt] = Lf[(size_t)(i * BS + rr) * M_N + tb + tt];
                }
                if (t == j) {
                    for (int idx = tid; idx < 32 * 32; idx += 512) {
                        int tt = idx >> 5, cc = idx & 31;
                        int gr = tb + tt, gc = c0 + cc;
                        Ws[tt][cc] = (gr >= gc) ? Wf[(size_t)gr * M_N + gc] : 0.0f;
                    }
                }
                __syncthreads();
                if (t == j) {
#pragma unroll
                    for (int tt = 0; tt < 32; ++tt) {
                        float l = Ls[rq][tt];
#pragma unroll
                        for (int c = 0; c < 8; ++c)
                            acc[c] = fmaf(l, Ws[tt][cq * 8 + c], acc[c]);
                    }
                } else {
                    const float (*Wh)[33] = Whist[t - j - 1];
#pragma unroll
                    for (int tt = 0; tt < 32; ++tt) {
                        float l = Ls[rq][tt];
#pragma unroll
                        for (int c = 0; c < 8; ++c)
                            acc[c] = fmaf(l, Wh[ch * 32 + tt][cq * 8 + c], acc[c]);
                    }
                }
            }
        }
        __syncthreads();
#pragma unroll
        for (int c = 0; c < 8; ++c) Ps[rq][cq * 8 + c] = acc[c];
        float a2[8];
#pragma unroll
        for (int c = 0; c < 8; ++c) a2[c] = 0.0f;
        for (int ch = 0; ch < 4; ++ch) {
            __syncthreads();
            for (int idx = tid; idx < 128 * 32; idx += 512) {
                int rr = idx >> 5, tt = idx & 31;
                Ls[rr][tt] = (rr >= ch * 32 + tt)
                           ? Wf[(size_t)(i * BS + rr) * M_N + i * BS + ch * 32 + tt] : 0.0f;
            }
            __syncthreads();
#pragma unroll
            for (int tt = 0; tt < 32; ++tt) {
                float l = Ls[rq][tt];
#pragma unroll
                for (int c = 0; c < 8; ++c)
                    a2[c] = fmaf(l, Ps[ch * 32 + tt][cq * 8 + c], a2[c]);
            }
        }
        __syncthreads();
#pragma unroll
        for (int c = 0; c < 8; ++c) {
            float v = -a2[c];
            Wf[(size_t)(i * BS + rq) * M_N + c0 + cq * 8 + c] = v;
            if (i < 7) Whist[i - j - 1][rq][cq * 8 + c] = v;
        }
        __syncthreads();
    }
}

// ---------------- pack W (fp32) into MFMA B-fragment order, fp16 hi/lo ----------------
__global__ void kw_pack(const float* __restrict__ Wf, _Float16* __restrict__ Wph,
                        _Float16* __restrict__ Wpl) {
    int T = blockIdx.x * 256 + threadIdx.x;
    int lane = T & 63, fid = T >> 6;
    int jn = fid & 63, kik = fid >> 6;
    int ki = kik & 3, kc = kik >> 2;
    int j  = jn * 16 + (lane & 15);
    int kb = kc * 128 + ki * 32 + (lane >> 4) * 8;
    f16x8 h, lo;
#pragma unroll
    for (int e = 0; e < 8; ++e) {
        int k = kb + e;
        float v = (k <= j) ? Wf[(size_t)j * M_N + k] : 0.0f;
        _Float16 hh = (_Float16)v;
        h[e]  = hh;
        lo[e] = (_Float16)(v - (float)hh);
    }
    size_t off = (size_t)fid * 512 + lane * 8;
    *(f16x8*)(Wph + off) = h;
    *(f16x8*)(Wpl + off) = lo;
}

// ---------------- main fused MFMA kernel: 32 rows x 1024 cols, FULL tile in LDS -------
// 64 KB LDS -> 2 blocks/CU; __launch_bounds__(512,4) requests 4 waves/EU.
__global__ __launch_bounds__(512, 4) void k_mm(const float* __restrict__ x_star,
                                               const float* __restrict__ pf,
                                               const float* __restrict__ Zst,
                                               const _Float16* __restrict__ Wph,
                                               const _Float16* __restrict__ Wpl,
                                               float* __restrict__ out, int Bq) {
    __shared__ __align__(16) char kls[32 * 2048];   // [row][1024 fp16], 16B-slot swizzled
    __shared__ float red_l[32];
    int tid  = threadIdx.x;
    int slab = blockIdx.x;
    int w = tid >> 6, lane = tid & 63;
    int lrow = lane & 15, kgrp = lane >> 4;

    // staging identity: row srow (0..31), col-group scc (8 cols = 16B) per chunk
    int scc = tid & 15, srow = tid >> 4;
    int q0 = slab * 32 + srow;
    int qa = (q0 < Bq) ? q0 : (Bq - 1);
    float xa0 = x_star[(size_t)qa * 5 + 0] * pf[0];
    float xa1 = x_star[(size_t)qa * 5 + 1] * pf[1];
    float xa2 = x_star[(size_t)qa * 5 + 2] * pf[2];
    float xa3 = x_star[(size_t)qa * 5 + 3] * pf[3];
    float xa4 = x_star[(size_t)qa * 5 + 4] * pf[4];
    float pv = pf[5];
    if (tid < 32) red_l[tid] = 0.0f;

    int swz = (srow & 15) << 4;
    // ---- stage the FULL 32x1024 tile: 8 chunks, no inner barriers ----
    for (int kc = 0; kc < 8; ++kc) {
        f16x8 h0;
#pragma unroll
        for (int bb = 0; bb < 2; ++bb) {
            int lb = kc * 128 + scc * 8 + bb * 4;
            float z0[4], z1[4], z2[4], z3[4], z4[4];
            *(float4*)z0 = *(const float4*)&Zst[lb];
            *(float4*)z1 = *(const float4*)&Zst[M_N + lb];
            *(float4*)z2 = *(const float4*)&Zst[2 * M_N + lb];
            *(float4*)z3 = *(const float4*)&Zst[3 * M_N + lb];
            *(float4*)z4 = *(const float4*)&Zst[4 * M_N + lb];
#pragma unroll
            for (int e = 0; e < 4; ++e) {
                float dx0 = xa0 - z0[e], dx1 = xa1 - z1[e], dx2 = xa2 - z2[e],
                      dx3 = xa3 - z3[e], dx4 = xa4 - z4[e];
                float d2 = dx0 * dx0 + dx1 * dx1 + dx2 * dx2 + dx3 * dx3 + dx4 * dx4;
                float dd = d2 + 1e-8f;
                float dist = sqrtf(dd);
                float sv = 2.23606798f * dist;
                h0[bb * 4 + e] = (_Float16)(pv * (1.0f + sv + 1.66666667f * dd) * __expf(-sv));
            }
        }
        int cb = kc * 256 + scc * 16;
        *(f16x8*)(&kls[srow * 2048 + (cb ^ swz)]) = h0;
    }
    __syncthreads();                             // the ONE barrier

    // ---- pure MFMA phase: 4 column groups of 16 jng each; acc[2][2] ----
    for (int jg = 0; jg < 4; ++jg) {
        f32x4 acc[2][2];
#pragma unroll
        for (int mi = 0; mi < 2; ++mi)
#pragma unroll
            for (int nj = 0; nj < 2; ++nj) acc[mi][nj] = (f32x4)(0.0f);

        int jng_hi = jg * 16 + 8 + ((w + 1) & 7);     // wave's max jng this group
        int jmax_w = jng_hi * 16 + 15;

        for (int kt = 0; kt < 32; ++kt) {
            int kmin = kt * 32;
            if (kmin > jmax_w) break;                 // wave-uniform
            f16x8 A_[2];
#pragma unroll
            for (int mi = 0; mi < 2; ++mi) {
                int row = mi * 16 + lrow;
                int cb  = kt * 64 + kgrp * 16;
                A_[mi] = *(const f16x8*)(&kls[row * 2048 + (cb ^ ((row & 15) << 4))]);
            }
#pragma unroll
            for (int nj = 0; nj < 2; ++nj) {
                int jng = jg * 16 + nj * 8 + ((w + nj) & 7);   // balanced interleave
                if (kmin > jng * 16 + 15) continue;            // all-zero W fragment
                size_t fo = ((size_t)(kt * 64 + jng)) * 512 + lane * 8;
                f16x8 Bh = *(const f16x8*)(Wph + fo);
                f16x8 Bl = *(const f16x8*)(Wpl + fo);
#pragma unroll
                for (int mi = 0; mi < 2; ++mi) {
                    acc[mi][nj] = __builtin_amdgcn_mfma_f32_16x16x32_f16(A_[mi], Bh, acc[mi][nj], 0, 0, 0);
                    acc[mi][nj] = __builtin_amdgcn_mfma_f32_16x16x32_f16(A_[mi], Bl, acc[mi][nj], 0, 0, 0);
                }
            }
        }

        // group epilogue: red[row] += y^2 (atomics; no barrier between groups)
#pragma unroll
        for (int mi = 0; mi < 2; ++mi) {
#pragma unroll
            for (int q = 0; q < 4; ++q) {
                float s = 0.0f;
#pragma unroll
                for (int nj = 0; nj < 2; ++nj) s = fmaf(acc[mi][nj][q], acc[mi][nj][q], s);
                s += __shfl_xor(s, 1);
                s += __shfl_xor(s, 2);
                s += __shfl_xor(s, 4);
                s += __shfl_xor(s, 8);
                if (lrow == 0) atomicAdd(&red_l[mi * 16 + kgrp * 4 + q], s);
            }
        }
    }
    __syncthreads();
    if (tid < 32) {
        int b = slab * 32 + tid;
        if (b < Bq) out[b] = sqrtf(fmaxf(pv - red_l[tid], 1e-6f));
    }
}

extern "C" void kernel_launch(void* const* d_in, const int* in_sizes, int n_in,
                              void* d_out, int out_size, void* d_ws, size_t ws_size,
                              hipStream_t stream) {
    const float* x_star  = (const float*)d_in[0];
    const float* log_ls  = (const float*)d_in[1];
    const float* log_var = (const float*)d_in[2];
    const float* Z_raw   = (const float*)d_in[3];
    float* out = (float*)d_out;
    int Bq = in_sizes[0] / 5;

    char* ws = (char*)d_ws;
    float*     Kf  = (float*)(ws + OFF_KF);
    float*     Lf  = (float*)(ws + OFF_LF);
    float*     Wf  = (float*)(ws + OFF_WF);
    _Float16*  Wph = (_Float16*)(ws + OFF_WPH);
    _Float16*  Wpl = (_Float16*)(ws + OFF_WPL);
    float*     pf  = (float*)(ws + OFF_PF);
    float*     Zst = (float*)(ws + OFF_ZT);

    k_build<<<4096, 256, 0, stream>>>(log_ls, log_var, Z_raw, Kf, pf, Zst);
    kw_diag<<<64, 512, 0, stream>>>(Kf, Wf, 0);
    for (int kb = 0; kb < NBK - 1; ++kb) {
        int nt = (NBK - 1 - kb) * 2;
        int grid = nt * (nt + 1) / 2 - 2;
        if (grid < 64) grid = 64;                // tiny-grid stall mitigation
        kw_step<<<grid, 256, 0, stream>>>(Kf, Wf, Lf, kb);
    }
    kw_trtri<<<dim3(4, 7), 512, 0, stream>>>(Lf, Wf);
    kw_pack<<<512, 256, 0, stream>>>(Wf, Wph, Wpl);

    int slabs = (Bq + 31) / 32;
    k_mm<<<slabs, 512, 0, stream>>>(x_star, pf, Zst, Wph, Wpl, out, Bq);
}